// Round 3
// baseline (265.572 us; speedup 1.0000x reference)
//
#include <hip/hip_runtime.h>
#include <math.h>

// Problem constants (b=16, n=512, h=1024)
#define NB 16
#define SEQ 512
#define HID 1024
#define XDIM 128       // 2*HEAD_SIZE
#define NHEADS 12
#define NROWS (NB*SEQ) // 8192
#define NEG_BIG 1000000000000.0f
#define MTILE 16

typedef __bf16 bf16x8 __attribute__((ext_vector_type(8)));
typedef __bf16 bf16x4 __attribute__((ext_vector_type(4)));
typedef float  f32x4  __attribute__((ext_vector_type(4)));

// ---------------------------------------------------------------------------
// Prep: W1T[n][k] = bf16(W1[k][n])  (128 x 1024 bf16, B^T layout for MFMA)
// ---------------------------------------------------------------------------
__global__ __launch_bounds__(256) void egp_prep(
    const float* __restrict__ W1, __bf16* __restrict__ W1T)
{
    int idx = blockIdx.x * 256 + threadIdx.x;   // 16384 threads
    int n   = idx >> 7;                         // 0..127
    int k0  = (idx & 127) << 3;                 // 0..1016 step 8
    bf16x8 o;
    #pragma unroll
    for (int j = 0; j < 8; j++)
        o[j] = (__bf16)W1[(size_t)(k0 + j) * XDIM + n];
    *(bf16x8*)(W1T + (size_t)n * HID + k0) = o;
}

// ---------------------------------------------------------------------------
// Stage 1 (MFMA): x = inp@W1 + b1 ; RoPE -> qw', kw' (bf16) ; bias=(x@W2+b2)/2
// Grid: 512 blocks x 256 threads (4 waves), 16 rows/block.
// A rows preloaded into 16 float4 regs up front (single HBM latency wave),
// converted chunk-by-chunk into LDS a-frag layout; B-frags direct from W1T
// in global (L2-resident). All three 16x16x32 bf16 frag layouts verified
// empirically in R2 (absmax matched pure-fp32 R0).
// ---------------------------------------------------------------------------
__global__ __launch_bounds__(256) void egp_stage1(
    const float* __restrict__ inp,   // (8192, 1024) fp32
    const __bf16* __restrict__ W1T,  // (128, 1024) bf16
    const float* __restrict__ b1,    // (128)
    const float* __restrict__ W2,    // (128, 24)
    const float* __restrict__ b2,    // (24)
    __bf16* __restrict__ qw,         // (8192, 64) bf16 row-major
    __bf16* __restrict__ kw,         // (8192, 64) bf16 row-major
    float* __restrict__ biasw)       // (8192, 24)  (already /2)
{
    __shared__ __bf16 As[2048];          // one 64-k chunk, a-frag order
    __shared__ float  Xs[MTILE][132];    // x rows for RoPE + bias GEMM
    __shared__ float  W2s[XDIM * 24];
    __shared__ float  b2s[24];

    const int t    = threadIdx.x;
    const int row0 = blockIdx.x * MTILE;
    const int lane = t & 63;
    const int w    = t >> 6;        // wave 0..3 -> cols [32w, 32w+32)
    const int quad = lane >> 4;
    const int mrow = lane & 15;
    const int ncol0 = w * 32;

    for (int i = t; i < XDIM * 24; i += 256) W2s[i] = W2[i];
    if (t < 24) b2s[t] = b2[t];

    // staging: thread t -> row m_st, k-offsets k_st..k_st+3 within each chunk
    const int m_st = t >> 4;
    const int k_st = (t & 15) * 4;
    const int s_st  = k_st >> 5;
    const int q_st  = (k_st & 31) >> 3;
    const int j_st  = k_st & 7;
    const int off_st = s_st * 1024 + q_st * 128 + m_st * 8 + j_st;
    const float* aptr = inp + (size_t)(row0 + m_st) * HID + k_st;

    // preload ALL 16 chunks' worth of A (one float4 per chunk) — issues 16
    // independent HBM loads back-to-back: one latency exposure, not 16.
    float4 v[16];
    #pragma unroll
    for (int c = 0; c < 16; c++)
        v[c] = *(const float4*)(aptr + 64 * c);

    f32x4 acc0 = {0.f, 0.f, 0.f, 0.f};
    f32x4 acc1 = {0.f, 0.f, 0.f, 0.f};

    #pragma unroll
    for (int c = 0; c < 16; c++) {
        const int kc = c * 64;
        __syncthreads();   // previous chunk's compute done before overwrite
        bf16x4 p;
        p[0] = (__bf16)v[c].x; p[1] = (__bf16)v[c].y;
        p[2] = (__bf16)v[c].z; p[3] = (__bf16)v[c].w;
        *(bf16x4*)(&As[off_st]) = p;
        __syncthreads();

        #pragma unroll
        for (int s2 = 0; s2 < 2; s2++) {
            bf16x8 a = *(bf16x8*)(&As[s2 * 1024 + quad * 128 + mrow * 8]);
            {
                const __bf16* bp = W1T + (size_t)(ncol0 + mrow) * HID
                                 + kc + s2 * 32 + quad * 8;
                bf16x8 b = *(const bf16x8*)(bp);
                acc0 = __builtin_amdgcn_mfma_f32_16x16x32_bf16(a, b, acc0, 0, 0, 0);
            }
            {
                const __bf16* bp = W1T + (size_t)(ncol0 + 16 + mrow) * HID
                                 + kc + s2 * 32 + quad * 8;
                bf16x8 b = *(const bf16x8*)(bp);
                acc1 = __builtin_amdgcn_mfma_f32_16x16x32_bf16(a, b, acc1, 0, 0, 0);
            }
        }
    }

    // epilogue: C/D layout col=lane&15, row=quad*4+reg
    float b1v0 = b1[ncol0 + mrow];
    float b1v1 = b1[ncol0 + 16 + mrow];
    #pragma unroll
    for (int r = 0; r < 4; r++) {
        Xs[quad * 4 + r][ncol0 + mrow]      = acc0[r] + b1v0;
        Xs[quad * 4 + r][ncol0 + 16 + mrow] = acc1[r] + b1v1;
    }
    __syncthreads();

    // RoPE. Thread owns x cols [8tx, 8tx+8) of row r; writes bf16x4.
    const int tx = t & 15;
    const int r  = t >> 4;
    const float LOG1E4 = 9.210340371976184f;  // ln(10000)
    float inv0 = expf(-((float)(2 * tx)     * (1.0f / 32.0f)) * LOG1E4);
    float inv1 = expf(-((float)(2 * tx + 1) * (1.0f / 32.0f)) * LOG1E4);
    {
        int grow  = row0 + r;
        float pos = (float)(grow & (SEQ - 1));
        float x[8];
        #pragma unroll
        for (int j = 0; j < 8; j++) x[j] = Xs[r][tx * 8 + j];
        float s0 = sinf(pos * inv0), c0 = cosf(pos * inv0);
        float s1 = sinf(pos * inv1), c1 = cosf(pos * inv1);
        bf16x4 q4, k4;
        q4[0] = (__bf16)(x[0] * c0 - x[2] * s0);
        q4[1] = (__bf16)(x[2] * c0 + x[0] * s0);
        q4[2] = (__bf16)(x[4] * c1 - x[6] * s1);
        q4[3] = (__bf16)(x[6] * c1 + x[4] * s1);
        k4[0] = (__bf16)(x[1] * c0 - x[3] * s0);
        k4[1] = (__bf16)(x[3] * c0 + x[1] * s0);
        k4[2] = (__bf16)(x[5] * c1 - x[7] * s1);
        k4[3] = (__bf16)(x[7] * c1 + x[5] * s1);
        *(bf16x4*)(qw + (size_t)grow * 64 + tx * 4) = q4;
        *(bf16x4*)(kw + (size_t)grow * 64 + tx * 4) = k4;
    }

    // bias GEMM: 16 rows x 24 cols
    for (int o = t; o < MTILE * 24; o += 256) {
        int row = o / 24;
        int jj  = o - row * 24;
        float s = 0.0f;
        for (int kk = 0; kk < XDIM; kk++)
            s += Xs[row][kk] * W2s[kk * 24 + jj];
        biasw[(size_t)(row0 + row) * 24 + jj] = (s + b2s[jj]) * 0.5f;
    }
}

// ---------------------------------------------------------------------------
// Stage 2 (MFMA): qk tile via 8 mfma/wave from global bf16 frags (no staging
// LDS, no scalar FMA loop, no bank-conflicted Ks reads). One-shot LDS
// transpose of the 64x64 tile, then the R1-proven 12-head float4 write loop.
// Grid: (8 n-tiles, 8 m-tiles, 16 batches) x 256 threads.
// ---------------------------------------------------------------------------
__global__ __launch_bounds__(256) void egp_stage2(
    const __bf16* __restrict__ qw,   // (8192, 64) bf16
    const __bf16* __restrict__ kw,   // (8192, 64) bf16
    const float* __restrict__ biasw,
    const float* __restrict__ am,    // (16, 512)
    float* __restrict__ out)         // (16, 12, 512, 512)
{
    __shared__ float Vals[64][68];   // qk tile (raw, unscaled)
    __shared__ float bEs[12][64];
    __shared__ float bOs[12][64];
    __shared__ float amN[64];
    __shared__ float amM[64];

    const int b  = blockIdx.z;
    const int m0 = blockIdx.y * 64;
    const int n0 = blockIdx.x * 64;
    const int t  = threadIdx.x;
    const int lane = t & 63;
    const int w    = t >> 6;    // wave w -> m rows [m0+16w, m0+16w+16)
    const int quad = lane >> 4;
    const int l16  = lane & 15;

    for (int o = t; o < 768; o += 256) {
        int nn = o & 63;
        int h  = o >> 6;
        bEs[h][nn] = biasw[(size_t)(b * SEQ + n0 + nn) * 24 + 2 * h];
        bOs[h][nn] = biasw[(size_t)(b * SEQ + m0 + nn) * 24 + 2 * h + 1];
    }
    if (t < 64)       amN[t]      = am[b * SEQ + n0 + t];
    else if (t < 128) amM[t - 64] = am[b * SEQ + m0 + (t - 64)];

    // A-frags: lane l16 = m row, quad*8+j = k  (16 B/lane, wave-linear 2 KB)
    const __bf16* qbase = qw + ((size_t)(b * SEQ + m0 + w * 16 + l16)) * 64 + quad * 8;
    bf16x8 a0 = *(const bf16x8*)(qbase);
    bf16x8 a1 = *(const bf16x8*)(qbase + 32);

    f32x4 acc[4];
    #pragma unroll
    for (int nt = 0; nt < 4; nt++) {
        const __bf16* kbase = kw + ((size_t)(b * SEQ + n0 + nt * 16 + l16)) * 64 + quad * 8;
        bf16x8 b0 = *(const bf16x8*)(kbase);
        bf16x8 b1 = *(const bf16x8*)(kbase + 32);
        f32x4 z = {0.f, 0.f, 0.f, 0.f};
        z = __builtin_amdgcn_mfma_f32_16x16x32_bf16(a0, b0, z, 0, 0, 0);
        z = __builtin_amdgcn_mfma_f32_16x16x32_bf16(a1, b1, z, 0, 0, 0);
        acc[nt] = z;
    }

    // C/D: col = l16 (n within tile), row = quad*4 + r (m within strip)
    #pragma unroll
    for (int nt = 0; nt < 4; nt++)
        #pragma unroll
        for (int r = 0; r < 4; r++)
            Vals[w * 16 + quad * 4 + r][nt * 16 + l16] = acc[nt][r];
    __syncthreads();

    // write phase (R1-proven): thread t -> rows ty*4.., cols tx*4.. (float4)
    const int tx = t & 15;
    const int ty = t >> 4;

    float amMv[4], amNv[4];
    #pragma unroll
    for (int i = 0; i < 4; i++) amMv[i] = amM[ty * 4 + i];
    #pragma unroll
    for (int j = 0; j < 4; j++) amNv[j] = amN[tx * 4 + j];

    float vals[4][4];
    #pragma unroll
    for (int i = 0; i < 4; i++) {
        int m = m0 + ty * 4 + i;
        float4 v4 = *(const float4*)(&Vals[ty * 4 + i][tx * 4]);
        float qk[4] = {v4.x, v4.y, v4.z, v4.w};
        #pragma unroll
        for (int j = 0; j < 4; j++) {
            int n = n0 + tx * 4 + j;
            float msk = (1.0f - amMv[i] * amNv[j]) * NEG_BIG
                      + ((n < m) ? NEG_BIG : 0.0f);
            vals[i][j] = qk[j] * 0.125f - msk;
        }
    }

    for (int h = 0; h < NHEADS; h++) {
        float be[4], bo[4];
        #pragma unroll
        for (int j = 0; j < 4; j++) be[j] = bEs[h][tx * 4 + j];
        #pragma unroll
        for (int i = 0; i < 4; i++) bo[i] = bOs[h][ty * 4 + i];
        float* obase = out + ((size_t)((b * NHEADS + h) * SEQ + m0 + ty * 4)) * SEQ + n0 + tx * 4;
        #pragma unroll
        for (int i = 0; i < 4; i++) {
            float4 o4;
            o4.x = vals[i][0] + be[0] + bo[i];
            o4.y = vals[i][1] + be[1] + bo[i];
            o4.z = vals[i][2] + be[2] + bo[i];
            o4.w = vals[i][3] + be[3] + bo[i];
            *(float4*)(obase + (size_t)i * SEQ) = o4;
        }
    }
}

extern "C" void kernel_launch(void* const* d_in, const int* in_sizes, int n_in,
                              void* d_out, int out_size, void* d_ws, size_t ws_size,
                              hipStream_t stream) {
    const float* inp = (const float*)d_in[0];   // (16,512,1024)
    const float* am  = (const float*)d_in[1];   // (16,512)
    const float* W1  = (const float*)d_in[2];   // (1024,128)
    const float* b1  = (const float*)d_in[3];   // (128)
    const float* W2  = (const float*)d_in[4];   // (128,24)
    const float* b2  = (const float*)d_in[5];   // (24)
    float* out = (float*)d_out;

    // workspace: qw bf16 (1MB) | kw bf16 (1MB) | bias f32 (768KB) | W1T (256KB)
    __bf16* qw   = (__bf16*)d_ws;
    __bf16* kw   = qw + (size_t)NROWS * 64;
    float*  bias = (float*)(kw + (size_t)NROWS * 64);
    __bf16* w1t  = (__bf16*)(bias + (size_t)NROWS * 24);

    egp_prep<<<64, 256, 0, stream>>>(W1, w1t);
    egp_stage1<<<NROWS / MTILE, 256, 0, stream>>>(inp, w1t, b1, W2, b2, qw, kw, bias);

    dim3 g2(SEQ / 64, SEQ / 64, NB);
    egp_stage2<<<g2, 256, 0, stream>>>(qw, kw, bias, am, out);
}

// Round 4
// 262.603 us; speedup vs baseline: 1.0113x; 1.0113x over previous
//
#include <hip/hip_runtime.h>
#include <math.h>

// Problem constants (b=16, n=512, h=1024)
#define NB 16
#define SEQ 512
#define HID 1024
#define XDIM 128       // 2*HEAD_SIZE
#define NHEADS 12
#define NROWS (NB*SEQ) // 8192
#define NEG_BIG 1000000000000.0f
#define MTILE 16

typedef __bf16 bf16x8 __attribute__((ext_vector_type(8)));
typedef __bf16 bf16x4 __attribute__((ext_vector_type(4)));
typedef float  f32x4  __attribute__((ext_vector_type(4)));

// ---------------------------------------------------------------------------
// Prep: W1T[n][k] = bf16(W1[k][n])  (128 x 1024 bf16, B^T layout for MFMA)
// ---------------------------------------------------------------------------
__global__ __launch_bounds__(256) void egp_prep(
    const float* __restrict__ W1, __bf16* __restrict__ W1T)
{
    int idx = blockIdx.x * 256 + threadIdx.x;   // 16384 threads
    int n   = idx >> 7;                         // 0..127
    int k0  = (idx & 127) << 3;                 // 0..1016 step 8
    bf16x8 o;
    #pragma unroll
    for (int j = 0; j < 8; j++)
        o[j] = (__bf16)W1[(size_t)(k0 + j) * XDIM + n];
    *(bf16x8*)(W1T + (size_t)n * HID + k0) = o;
}

// ---------------------------------------------------------------------------
// Stage 1 (unchanged from R3): x = inp@W1 + b1 ; RoPE -> qw', kw' (bf16);
// bias=(x@W2+b2)/2
// ---------------------------------------------------------------------------
__global__ __launch_bounds__(256) void egp_stage1(
    const float* __restrict__ inp,   // (8192, 1024) fp32
    const __bf16* __restrict__ W1T,  // (128, 1024) bf16
    const float* __restrict__ b1,    // (128)
    const float* __restrict__ W2,    // (128, 24)
    const float* __restrict__ b2,    // (24)
    __bf16* __restrict__ qw,         // (8192, 64) bf16 row-major
    __bf16* __restrict__ kw,         // (8192, 64) bf16 row-major
    float* __restrict__ biasw)       // (8192, 24)  (already /2)
{
    __shared__ __bf16 As[2048];          // one 64-k chunk, a-frag order
    __shared__ float  Xs[MTILE][132];    // x rows for RoPE + bias GEMM
    __shared__ float  W2s[XDIM * 24];
    __shared__ float  b2s[24];

    const int t    = threadIdx.x;
    const int row0 = blockIdx.x * MTILE;
    const int lane = t & 63;
    const int w    = t >> 6;        // wave 0..3 -> cols [32w, 32w+32)
    const int quad = lane >> 4;
    const int mrow = lane & 15;
    const int ncol0 = w * 32;

    for (int i = t; i < XDIM * 24; i += 256) W2s[i] = W2[i];
    if (t < 24) b2s[t] = b2[t];

    const int m_st = t >> 4;
    const int k_st = (t & 15) * 4;
    const int s_st  = k_st >> 5;
    const int q_st  = (k_st & 31) >> 3;
    const int j_st  = k_st & 7;
    const int off_st = s_st * 1024 + q_st * 128 + m_st * 8 + j_st;
    const float* aptr = inp + (size_t)(row0 + m_st) * HID + k_st;

    float4 v[16];
    #pragma unroll
    for (int c = 0; c < 16; c++)
        v[c] = *(const float4*)(aptr + 64 * c);

    f32x4 acc0 = {0.f, 0.f, 0.f, 0.f};
    f32x4 acc1 = {0.f, 0.f, 0.f, 0.f};

    #pragma unroll
    for (int c = 0; c < 16; c++) {
        const int kc = c * 64;
        __syncthreads();
        bf16x4 p;
        p[0] = (__bf16)v[c].x; p[1] = (__bf16)v[c].y;
        p[2] = (__bf16)v[c].z; p[3] = (__bf16)v[c].w;
        *(bf16x4*)(&As[off_st]) = p;
        __syncthreads();

        #pragma unroll
        for (int s2 = 0; s2 < 2; s2++) {
            bf16x8 a = *(bf16x8*)(&As[s2 * 1024 + quad * 128 + mrow * 8]);
            {
                const __bf16* bp = W1T + (size_t)(ncol0 + mrow) * HID
                                 + kc + s2 * 32 + quad * 8;
                bf16x8 b = *(const bf16x8*)(bp);
                acc0 = __builtin_amdgcn_mfma_f32_16x16x32_bf16(a, b, acc0, 0, 0, 0);
            }
            {
                const __bf16* bp = W1T + (size_t)(ncol0 + 16 + mrow) * HID
                                 + kc + s2 * 32 + quad * 8;
                bf16x8 b = *(const bf16x8*)(bp);
                acc1 = __builtin_amdgcn_mfma_f32_16x16x32_bf16(a, b, acc1, 0, 0, 0);
            }
        }
    }

    float b1v0 = b1[ncol0 + mrow];
    float b1v1 = b1[ncol0 + 16 + mrow];
    #pragma unroll
    for (int r = 0; r < 4; r++) {
        Xs[quad * 4 + r][ncol0 + mrow]      = acc0[r] + b1v0;
        Xs[quad * 4 + r][ncol0 + 16 + mrow] = acc1[r] + b1v1;
    }
    __syncthreads();

    const int tx = t & 15;
    const int r  = t >> 4;
    const float LOG1E4 = 9.210340371976184f;  // ln(10000)
    float inv0 = expf(-((float)(2 * tx)     * (1.0f / 32.0f)) * LOG1E4);
    float inv1 = expf(-((float)(2 * tx + 1) * (1.0f / 32.0f)) * LOG1E4);
    {
        int grow  = row0 + r;
        float pos = (float)(grow & (SEQ - 1));
        float x[8];
        #pragma unroll
        for (int j = 0; j < 8; j++) x[j] = Xs[r][tx * 8 + j];
        float s0 = sinf(pos * inv0), c0 = cosf(pos * inv0);
        float s1 = sinf(pos * inv1), c1 = cosf(pos * inv1);
        bf16x4 q4, k4;
        q4[0] = (__bf16)(x[0] * c0 - x[2] * s0);
        q4[1] = (__bf16)(x[2] * c0 + x[0] * s0);
        q4[2] = (__bf16)(x[4] * c1 - x[6] * s1);
        q4[3] = (__bf16)(x[6] * c1 + x[4] * s1);
        k4[0] = (__bf16)(x[1] * c0 - x[3] * s0);
        k4[1] = (__bf16)(x[3] * c0 + x[1] * s0);
        k4[2] = (__bf16)(x[5] * c1 - x[7] * s1);
        k4[3] = (__bf16)(x[7] * c1 + x[5] * s1);
        *(bf16x4*)(qw + (size_t)grow * 64 + tx * 4) = q4;
        *(bf16x4*)(kw + (size_t)grow * 64 + tx * 4) = k4;
    }

    for (int o = t; o < MTILE * 24; o += 256) {
        int row = o / 24;
        int jj  = o - row * 24;
        float s = 0.0f;
        for (int kk = 0; kk < XDIM; kk++)
            s += Xs[row][kk] * W2s[kk * 24 + jj];
        biasw[(size_t)(row0 + row) * 24 + jj] = (s + b2s[jj]) * 0.5f;
    }
}

// ---------------------------------------------------------------------------
// Stage 2 v3: m-tile 16 x FULL n=512. Per (block, head) the output region is
// one contiguous 32 KB span, written flat — fill-kernel-like linear streams.
// QK via 16 MFMAs/wave from global bf16 frags; mask+scale folded at the
// C->LDS store; Vals padded to stride 516 (quad rows land on distinct banks).
// Grid: (32 m-tiles, 16 batches), 256 threads.
// ---------------------------------------------------------------------------
__global__ __launch_bounds__(256) void egp_stage2(
    const __bf16* __restrict__ qw,   // (8192, 64) bf16
    const __bf16* __restrict__ kw,   // (8192, 64) bf16
    const float* __restrict__ biasw, // (8192, 24)
    const float* __restrict__ am,    // (16, 512)
    float* __restrict__ out)         // (16, 12, 512, 512)
{
    __shared__ float Vals[MTILE][516];   // masked+scaled qk tile, ~33 KB
    __shared__ float bEs[NHEADS][512];   // 24 KB
    __shared__ float bOs[NHEADS][MTILE];
    __shared__ float amN[512];
    __shared__ float amM[MTILE];

    const int b  = blockIdx.y;
    const int m0 = blockIdx.x * MTILE;
    const int t  = threadIdx.x;
    const int lane = t & 63;
    const int w    = t >> 6;
    const int quad = lane >> 4;
    const int l16  = lane & 15;

    // --- stage LDS: masks + per-head biases ---
    #pragma unroll
    for (int u = 0; u < 2; u++) amN[t + 256 * u] = am[b * SEQ + t + 256 * u];
    if (t < MTILE) amM[t] = am[b * SEQ + m0 + t];
    for (int o = t; o < NHEADS * MTILE; o += 256) {
        int h  = o >> 4;
        int mm = o & 15;
        bOs[h][mm] = biasw[(size_t)(b * SEQ + m0 + mm) * 24 + 2 * h + 1];
    }
    for (int o = t; o < NHEADS * 512; o += 256) {
        int h = o >> 9;
        int n = o & 511;
        bEs[h][n] = biasw[(size_t)(b * SEQ + n) * 24 + 2 * h];
    }

    // --- QK MFMA: wave w covers n-strips nt = 8w..8w+7 ---
    const __bf16* qbase = qw + ((size_t)(b * SEQ + m0 + l16)) * 64 + quad * 8;
    bf16x8 a0 = *(const bf16x8*)(qbase);
    bf16x8 a1 = *(const bf16x8*)(qbase + 32);

    f32x4 acc[8];
    #pragma unroll
    for (int u = 0; u < 8; u++) {
        int nt = w * 8 + u;
        const __bf16* kbase = kw + ((size_t)(b * SEQ + nt * 16 + l16)) * 64 + quad * 8;
        bf16x8 b0 = *(const bf16x8*)(kbase);
        bf16x8 b1 = *(const bf16x8*)(kbase + 32);
        f32x4 z = {0.f, 0.f, 0.f, 0.f};
        z = __builtin_amdgcn_mfma_f32_16x16x32_bf16(a0, b0, z, 0, 0, 0);
        z = __builtin_amdgcn_mfma_f32_16x16x32_bf16(a1, b1, z, 0, 0, 0);
        acc[u] = z;
    }

    // --- fold scale + masks, store to LDS (C/D: col=l16, row=quad*4+r) ---
    #pragma unroll
    for (int u = 0; u < 8; u++) {
        int n = w * 128 + u * 16 + l16;
        float an = amN[n];
        #pragma unroll
        for (int r = 0; r < 4; r++) {
            int mloc = quad * 4 + r;
            int m    = m0 + mloc;
            float msk = (1.0f - amM[mloc] * an) * NEG_BIG
                      + ((n < m) ? NEG_BIG : 0.0f);
            Vals[mloc][n] = acc[u][r] * 0.125f - msk;
        }
    }
    __syncthreads();

    // --- write phase: per head, flat contiguous 32 KB span ---
    // f4 = t + 256*it (it=0..7): row = f4>>7, col4 = f4&127.
    // Wave writes 1 KB contiguous per store instruction; block streams 32 KB
    // linearly per head.
    #pragma unroll
    for (int h = 0; h < NHEADS; h++) {
        float* hbase = out + ((size_t)((b * NHEADS + h) * SEQ + m0)) * SEQ;
        #pragma unroll
        for (int it = 0; it < 8; it++) {
            int f4   = t + 256 * it;
            int row  = f4 >> 7;
            int col4 = f4 & 127;
            float4 v = *(const float4*)(&Vals[row][col4 * 4]);
            float4 e = *(const float4*)(&bEs[h][col4 * 4]);
            float  bo = bOs[h][row];
            float4 o4;
            o4.x = v.x + e.x + bo;
            o4.y = v.y + e.y + bo;
            o4.z = v.z + e.z + bo;
            o4.w = v.w + e.w + bo;
            *(float4*)(hbase + (size_t)f4 * 4) = o4;
        }
    }
}

extern "C" void kernel_launch(void* const* d_in, const int* in_sizes, int n_in,
                              void* d_out, int out_size, void* d_ws, size_t ws_size,
                              hipStream_t stream) {
    const float* inp = (const float*)d_in[0];   // (16,512,1024)
    const float* am  = (const float*)d_in[1];   // (16,512)
    const float* W1  = (const float*)d_in[2];   // (1024,128)
    const float* b1  = (const float*)d_in[3];   // (128)
    const float* W2  = (const float*)d_in[4];   // (128,24)
    const float* b2  = (const float*)d_in[5];   // (24)
    float* out = (float*)d_out;

    // workspace: qw bf16 (1MB) | kw bf16 (1MB) | bias f32 (768KB) | W1T (256KB)
    __bf16* qw   = (__bf16*)d_ws;
    __bf16* kw   = qw + (size_t)NROWS * 64;
    float*  bias = (float*)(kw + (size_t)NROWS * 64);
    __bf16* w1t  = (__bf16*)(bias + (size_t)NROWS * 24);

    egp_prep<<<64, 256, 0, stream>>>(W1, w1t);
    egp_stage1<<<NROWS / MTILE, 256, 0, stream>>>(inp, w1t, b1, W2, b2, qw, kw, bias);

    dim3 g2(SEQ / MTILE, NB);
    egp_stage2<<<g2, 256, 0, stream>>>(qw, kw, bias, am, out);
}